// Round 1
// baseline (127.767 us; speedup 1.0000x reference)
//
#include <hip/hip_runtime.h>

// Problem constants (from reference setup)
#define BB 2
#define LL 128
#define HH 768
#define H2 1536          // 2*H
#define CC 6
#define NTOK (BB * LL)   // 256

// Workspace layout (float offsets)
#define WFC_OFF   0                         // Wfc = Wf @ cls_w            (1536 x 6)
#define WFWFC_OFF 9216                      // WfWfc = Wf @ Wfc            (1536 x 6)
#define SM_OFF    18432                     // small matrices/vectors      (240 floats)
//   within SM: K1=0, M3=36, M4=72, K2=108, M3f=144, M4f=180, d1=216, dbfc=222, gamma=228, Cfin=234
#define TOK_OFF   18672                     // 8 per-token arrays of NTOK*CC floats:
//   0:p 1:q 2:r1 3:r2 4:s1 5:s2 6:Afin 7:Bfin

// ---------------------------------------------------------------------------
// out[k*6+c] = sum_r A[k*1536+r] * Bm[r*6+c]   for k in [0,1536)
// Used for Wfc (A=feat_w rows 0..1535, Bm=cls_w) and WfWfc (Bm=Wfc).
__global__ __launch_bounds__(256) void matcol_kernel(const float* __restrict__ A,
                                                     const float* __restrict__ Bm,
                                                     float* __restrict__ out) {
    int k = blockIdx.x;
    int tid = threadIdx.x;
    float acc[CC] = {0.f, 0.f, 0.f, 0.f, 0.f, 0.f};
    const float* arow = A + (size_t)k * H2;
    for (int r = tid; r < H2; r += 256) {
        float w = arow[r];
        const float* brow = Bm + r * CC;
#pragma unroll
        for (int c = 0; c < CC; ++c) acc[c] += w * brow[c];
    }
#pragma unroll
    for (int c = 0; c < CC; ++c) {
#pragma unroll
        for (int off = 32; off > 0; off >>= 1) acc[c] += __shfl_down(acc[c], off, 64);
    }
    __shared__ float sred[4][CC];
    int wave = tid >> 6, lane = tid & 63;
    if (lane == 0) {
#pragma unroll
        for (int c = 0; c < CC; ++c) sred[wave][c] = acc[c];
    }
    __syncthreads();
    if (tid < CC) {
        out[k * CC + tid] = sred[0][tid] + sred[1][tid] + sred[2][tid] + sred[3][tid];
    }
}

// ---------------------------------------------------------------------------
// 240 dot-products of length 1536:
//  tasks 0..215 : the six 6x6 matrices K1,M3,M4 (vs cls_w) and K2,M3f,M4f (vs Wfc)
//  tasks 216..221: d1[c]  = feat_b @ cls_w[:,c] + cls_b[c]
//  tasks 222..227: dbfc[c]= feat_b @ Wfc[:,c]
__global__ __launch_bounds__(256) void dots_kernel(const float* __restrict__ feat_w,
                                                   const float* __restrict__ cls_w,
                                                   const float* __restrict__ cls_b,
                                                   const float* __restrict__ feat_b,
                                                   float* __restrict__ ws) {
    const float* Wfc = ws + WFC_OFF;
    int task = blockIdx.x, tid = threadIdx.x;
    const float* va;
    const float* mb;
    int c, outIdx;
    bool add_clsb = false;
    if (task < 216) {
        int m = task / 36, e = task % 36, cp = e / CC;
        c = e % CC;
        int mm = m % 3; // 0 -> W5 row base, 1 -> W3, 2 -> W4
        int row = (mm == 0) ? (H2 + 2 * CC) : ((mm == 1) ? H2 : (H2 + CC));
        va = feat_w + (size_t)(row + cp) * H2;
        mb = (m < 3) ? cls_w : Wfc;
        outIdx = m * 36 + e;
    } else {
        int e = task - 216;
        c = e % CC;
        va = feat_b;
        mb = (e < CC) ? cls_w : Wfc;
        outIdx = 216 + e;
        add_clsb = (e < CC);
    }
    float acc = 0.f;
    for (int r = tid; r < H2; r += 256) acc += va[r] * mb[r * CC + c];
#pragma unroll
    for (int off = 32; off > 0; off >>= 1) acc += __shfl_down(acc, off, 64);
    __shared__ float sred[4];
    int wave = tid >> 6, lane = tid & 63;
    if (lane == 0) sred[wave] = acc;
    __syncthreads();
    if (tid == 0) {
        float v = sred[0] + sred[1] + sred[2] + sred[3];
        if (add_clsb) v += cls_b[c];
        ws[SM_OFF + outIdx] = v;
    }
}

// ---------------------------------------------------------------------------
// gamma = cls_b@K1 + d1 ; Cfin = dbfc + d1 + cls_b@K2 + gamma@K1
__global__ void combos_kernel(const float* __restrict__ cls_b, float* __restrict__ ws) {
    float* sm = ws + SM_OFF;
    int c = threadIdx.x;
    if (c < CC) {
        float g = sm[216 + c];
        for (int cp = 0; cp < CC; ++cp) g += cls_b[cp] * sm[0 + cp * CC + c];
        sm[228 + c] = g;
    }
    __syncthreads();
    if (c < CC) {
        float f = sm[222 + c] + sm[216 + c];
        for (int cp = 0; cp < CC; ++cp) f += cls_b[cp] * sm[108 + cp * CC + c];
        for (int cp = 0; cp < CC; ++cp) f += sm[228 + cp] * sm[0 + cp * CC + c];
        sm[234 + c] = f;
    }
}

// ---------------------------------------------------------------------------
// Per-token projections of hidden against six (768 x 6) column blocks:
//  p = h@cls_w[:H], q = h@cls_w[H:], r1 = h@Wfc[:H], r2 = h@Wfc[H:],
//  s1 = h@WfWfc[:H], s2 = h@WfWfc[H:]
__global__ __launch_bounds__(256) void token_kernel(const float* __restrict__ hidden,
                                                    const float* __restrict__ cls_w,
                                                    float* __restrict__ ws) {
    const float* Wfc = ws + WFC_OFF;
    const float* Wf2 = ws + WFWFC_OFF;
    int tok = blockIdx.x, tid = threadIdx.x;
    float acc[6][CC] = {};
    const float* hrow = hidden + (size_t)tok * HH;
    for (int k = tid; k < HH; k += 256) {
        float hk = hrow[k];
        const float* c0 = cls_w + k * CC;
        const float* c1 = cls_w + (HH + k) * CC;
        const float* w0 = Wfc + k * CC;
        const float* w1 = Wfc + (HH + k) * CC;
        const float* v0 = Wf2 + k * CC;
        const float* v1 = Wf2 + (HH + k) * CC;
#pragma unroll
        for (int c = 0; c < CC; ++c) {
            acc[0][c] += hk * c0[c];
            acc[1][c] += hk * c1[c];
            acc[2][c] += hk * w0[c];
            acc[3][c] += hk * w1[c];
            acc[4][c] += hk * v0[c];
            acc[5][c] += hk * v1[c];
        }
    }
#pragma unroll
    for (int g = 0; g < 6; ++g)
#pragma unroll
        for (int c = 0; c < CC; ++c)
#pragma unroll
            for (int off = 32; off > 0; off >>= 1) acc[g][c] += __shfl_down(acc[g][c], off, 64);
    __shared__ float sred[4][6][CC];
    int wave = tid >> 6, lane = tid & 63;
    if (lane == 0) {
#pragma unroll
        for (int g = 0; g < 6; ++g)
#pragma unroll
            for (int c = 0; c < CC; ++c) sred[wave][g][c] = acc[g][c];
    }
    __syncthreads();
    if (tid < 36) {
        int g = tid / CC, c = tid % CC;
        float s = sred[0][g][c] + sred[1][g][c] + sred[2][g][c] + sred[3][g][c];
        ws[TOK_OFF + g * (NTOK * CC) + tok * CC + c] = s;
    }
}

// ---------------------------------------------------------------------------
// Fused plane stage per batch: pooled0 -> alpha/beta -> pooled1 -> Afin/Bfin.
// Block b = batch b, 768 threads = (t in [0,128)) x (c in [0,6)).
__global__ __launch_bounds__(768) void plane_kernel(const float* __restrict__ mask_in,
                                                    const float* __restrict__ cls_b_g,
                                                    float* __restrict__ ws) {
    int b = blockIdx.x;
    int tid = threadIdx.x;
    int t = tid / CC, c = tid % CC;
    __shared__ float p_sh[LL][CC], q_sh[LL][CC], m_sh[LL], cb_sh[CC];
    __shared__ float sm_sh[240];
    __shared__ float pool0[LL][CC], al[LL][CC], be[LL][CC], pool1[LL][CC];
    const float* tokbase = ws + TOK_OFF;
    int tok = b * LL + t;
    p_sh[t][c] = tokbase[0 * (NTOK * CC) + tok * CC + c];
    q_sh[t][c] = tokbase[1 * (NTOK * CC) + tok * CC + c];
    if (tid < LL) m_sh[tid] = mask_in[b * LL + tid];
    if (tid < 240) sm_sh[tid] = ws[SM_OFF + tid];
    if (tid < CC) cb_sh[tid] = cls_b_g[tid];
    __syncthreads();
    // pooled0: max over masked column t and row t of probs0 = p_i + q_j + cls_b
    {
        float pt = p_sh[t][c], qt = q_sh[t][c], cb = cb_sh[c], mt = m_sh[t];
        float best = -INFINITY;
        for (int i = 0; i < LL; ++i) {
            float mi = m_sh[i];
            float col = (i <= t) ? (p_sh[i][c] + qt + cb) * (mi * mt) : 0.0f;
            float row = (t <= i) ? (pt + q_sh[i][c] + cb) * (mt * mi) : 0.0f;
            best = fmaxf(best, fmaxf(col, row));
        }
        pool0[t][c] = best;
    }
    __syncthreads();
    // alpha = r1 + pooled0@M3 + p@K1 ; beta = r2 + pooled0@M4 + q@K1
    {
        float a = tokbase[2 * (NTOK * CC) + tok * CC + c];
        float bv = tokbase[3 * (NTOK * CC) + tok * CC + c];
        for (int cp = 0; cp < CC; ++cp) {
            a += pool0[t][cp] * sm_sh[36 + cp * CC + c];
            a += p_sh[t][cp] * sm_sh[0 + cp * CC + c];
            bv += pool0[t][cp] * sm_sh[72 + cp * CC + c];
            bv += q_sh[t][cp] * sm_sh[0 + cp * CC + c];
        }
        al[t][c] = a;
        be[t][c] = bv;
    }
    __syncthreads();
    // pooled1 on probs1 = alpha_i + beta_j + gamma
    {
        float at = al[t][c], bt = be[t][c], g = sm_sh[228 + c], mt = m_sh[t];
        float best = -INFINITY;
        for (int i = 0; i < LL; ++i) {
            float mi = m_sh[i];
            float col = (i <= t) ? (al[i][c] + bt + g) * (mi * mt) : 0.0f;
            float row = (t <= i) ? (at + be[i][c] + g) * (mt * mi) : 0.0f;
            best = fmaxf(best, fmaxf(col, row));
        }
        pool1[t][c] = best;
    }
    __syncthreads();
    // Afin = s1 + pooled0@M3f + pooled1@M3 + p@K2 + alpha@K1
    // Bfin = s2 + pooled0@M4f + pooled1@M4 + q@K2 + beta@K1
    {
        float A = tokbase[4 * (NTOK * CC) + tok * CC + c];
        float Bv = tokbase[5 * (NTOK * CC) + tok * CC + c];
        for (int cp = 0; cp < CC; ++cp) {
            A += pool0[t][cp] * sm_sh[144 + cp * CC + c];
            A += pool1[t][cp] * sm_sh[36 + cp * CC + c];
            A += p_sh[t][cp] * sm_sh[108 + cp * CC + c];
            A += al[t][cp] * sm_sh[0 + cp * CC + c];
            Bv += pool0[t][cp] * sm_sh[180 + cp * CC + c];
            Bv += pool1[t][cp] * sm_sh[72 + cp * CC + c];
            Bv += q_sh[t][cp] * sm_sh[108 + cp * CC + c];
            Bv += be[t][cp] * sm_sh[0 + cp * CC + c];
        }
        ws[TOK_OFF + 6 * (NTOK * CC) + tok * CC + c] = A;
        ws[TOK_OFF + 7 * (NTOK * CC) + tok * CC + c] = Bv;
    }
}

// ---------------------------------------------------------------------------
// out[b,i,j,c] = Afin[b,i,c] + Bfin[b,j,c] + Cfin[c]
__global__ __launch_bounds__(256) void out_kernel(const float* __restrict__ ws,
                                                  float* __restrict__ out) {
    int tid = blockIdx.x * 256 + threadIdx.x;
    if (tid >= BB * LL * LL * CC) return;
    int c = tid % CC;
    int j = (tid / CC) % LL;
    int rest = tid / (CC * LL);
    int i = rest % LL;
    int b = rest / LL;
    const float* Af = ws + TOK_OFF + 6 * (NTOK * CC);
    const float* Bf = ws + TOK_OFF + 7 * (NTOK * CC);
    out[tid] = Af[(b * LL + i) * CC + c] + Bf[(b * LL + j) * CC + c] + ws[SM_OFF + 234 + c];
}

// ---------------------------------------------------------------------------
extern "C" void kernel_launch(void* const* d_in, const int* in_sizes, int n_in,
                              void* d_out, int out_size, void* d_ws, size_t ws_size,
                              hipStream_t stream) {
    const float* hidden = (const float*)d_in[0];          // (2,128,768)
    const float* attention_mask = (const float*)d_in[1];  // (2,128)
    const float* cls_w = (const float*)d_in[2];           // (1536,6)
    const float* cls_b = (const float*)d_in[3];           // (6,)
    const float* feat_w = (const float*)d_in[4];          // (1554,1536)
    const float* feat_b = (const float*)d_in[5];          // (1536,)
    // d_in[6] = nhops (fixed at 2 by setup; hardcoded)
    float* out = (float*)d_out;
    float* ws = (float*)d_ws;

    matcol_kernel<<<H2, 256, 0, stream>>>(feat_w, cls_w, ws + WFC_OFF);
    matcol_kernel<<<H2, 256, 0, stream>>>(feat_w, ws + WFC_OFF, ws + WFWFC_OFF);
    dots_kernel<<<240, 256, 0, stream>>>(feat_w, cls_w, cls_b, feat_b, ws);
    combos_kernel<<<1, 64, 0, stream>>>(cls_b, ws);
    token_kernel<<<NTOK, 256, 0, stream>>>(hidden, cls_w, ws);
    plane_kernel<<<BB, 768, 0, stream>>>(attention_mask, cls_b, ws);
    out_kernel<<<(BB * LL * LL * CC + 255) / 256, 256, 0, stream>>>(ws, out);
}